// Round 1
// 26292.877 us; speedup vs baseline: 3.5096x; 3.5096x over previous
//
#include <hip/hip_runtime.h>

typedef short v8s __attribute__((ext_vector_type(8)));
typedef float v4f __attribute__((ext_vector_type(4)));
typedef int   v4i __attribute__((ext_vector_type(4)));

#define T_SEQ 512
#define BATCH 64
#define NH    1024
#define TC    16   // time-chunk length (G buffer covers TC steps)

__device__ __forceinline__ ushort f2bf(float f) {
    union { float f; unsigned int i; } v; v.f = f;
    unsigned int x = v.i;
    return (ushort)((x + 0x7fffu + ((x >> 16) & 1u)) >> 16);
}
__device__ __forceinline__ float sigm(float x) { return 1.0f / (1.0f + __expf(-x)); }
__device__ __forceinline__ float tanhx(float x) {
    float e = __expf(2.0f * x);           // inf-safe: x>>0 -> 1, x<<0 -> -1
    return 1.0f - 2.0f / (e + 1.0f);
}
// convert 8 consecutive fp32 -> 8 bf16 packed, store to LDS/regs dst
__device__ __forceinline__ void stage8_f32(ushort* dst, const float* src) {
    float4 a = *(const float4*)src;
    float4 b = *(const float4*)(src + 4);
    ushort t[8] = {f2bf(a.x), f2bf(a.y), f2bf(a.z), f2bf(a.w),
                   f2bf(b.x), f2bf(b.y), f2bf(b.z), f2bf(b.w)};
    *(int4*)dst = *(int4*)t;
}
__device__ __forceinline__ v8s load8_f32(const float* src) {
    float4 a = *(const float4*)src;
    float4 b = *(const float4*)(src + 4);
    ushort t[8] = {f2bf(a.x), f2bf(a.y), f2bf(a.z), f2bf(a.w),
                   f2bf(b.x), f2bf(b.y), f2bf(b.z), f2bf(b.w)};
    return *(v8s*)t;
}

// ---- device-coherent (LLC, L2-bypass) access helpers: sc0 sc1 -----------
__device__ __forceinline__ v4i llc_load_i4(const void* p) {
    v4i r;
    asm volatile("global_load_dwordx4 %0, %1, off sc0 sc1" : "=v"(r) : "v"(p));
    return r;
}
__device__ __forceinline__ v4f llc_load_f4(const float* p) {
    v4f r;
    asm volatile("global_load_dwordx4 %0, %1, off sc0 sc1" : "=v"(r) : "v"(p));
    return r;
}
__device__ __forceinline__ unsigned int llc_load_u32(const unsigned int* p) {
    unsigned int r;
    asm volatile("global_load_dword %0, %1, off sc0 sc1\n\ts_waitcnt vmcnt(0)"
                 : "=v"(r) : "v"(p) : "memory");
    return r;
}
__device__ __forceinline__ void llc_store_f32(float* p, float v) {
    asm volatile("global_store_dword %0, %1, off sc0 sc1" :: "v"(p), "v"(v) : "memory");
}
__device__ __forceinline__ void llc_store_u16(ushort* p, ushort v) {
    unsigned int vv = v;
    asm volatile("global_store_short %0, %1, off sc0 sc1" :: "v"(p), "v"(vv) : "memory");
}

// ---------------------------------------------------------------------------
// Input-projection GEMM (unchanged from previous round).
// G[(s*64+b)*4096 + j] = sum_k A(s,b,k)*W[j][k] + bias[j]
// mode 0: A = X[(b*512 + tstart + s*tstep)*1024 + k]                 (K=1024)
// mode 1: k<1024 : hfc[(((tstart+s)&15)*64 + b)*1024 + k]   (bf16 circular)
//         k>=1024: enc[(b*512 + tstart+s)*1024 + (k-1024)]  (fp32 hb in enc)
// ---------------------------------------------------------------------------
__global__ __launch_bounds__(256)
void gates_gemm(const float* __restrict__ A0f, const ushort* __restrict__ A0h,
                const float* __restrict__ A1f,
                const float* __restrict__ W, const float* __restrict__ bias,
                float* __restrict__ G, int tstart, int tstep, int K, int mode)
{
    __shared__ ushort As[128][32];
    __shared__ ushort Bs[128][32];
    const int tid  = threadIdx.x;
    const int lane = tid & 63;
    const int wave = tid >> 6;
    const int wm   = (wave >> 1) * 64;
    const int wn   = (wave & 1) * 64;
    const int r    = lane & 15;
    const int q    = lane >> 4;
    const int tm   = blockIdx.x;
    const int tn   = blockIdx.y;

    v4f acc[4][4] = {};

    const int nkb = K >> 5;
    for (int kb = 0; kb < nkb; ++kb) {
        const int k0 = kb << 5;
        __syncthreads();
        #pragma unroll
        for (int j = 0; j < 2; ++j) {
            int c   = tid * 2 + j;
            int row = c >> 2;
            int k8  = (c & 3) << 3;
            int kg  = k0 + k8;
            int m = tm * 128 + row;
            int s = m >> 6, b = m & 63;
            if (mode == 0) {
                int t = tstart + s * tstep;
                stage8_f32(&As[row][k8], A0f + ((size_t)b * T_SEQ + t) * NH + kg);
            } else {
                int t = tstart + s;
                if (kg < NH) {
                    *(int4*)(&As[row][k8]) =
                        *(const int4*)(A0h + (((size_t)(t & (TC - 1)) * BATCH) + b) * NH + kg);
                } else {
                    stage8_f32(&As[row][k8], A1f + ((size_t)b * T_SEQ + t) * NH + (kg - NH));
                }
            }
            int jr = tn * 128 + row;
            stage8_f32(&Bs[row][k8], W + (size_t)jr * K + kg);
        }
        __syncthreads();
        v8s af[4], bfv[4];
        #pragma unroll
        for (int i = 0; i < 4; ++i) af[i]  = *(const v8s*)(&As[wm + i * 16 + r][q * 8]);
        #pragma unroll
        for (int i = 0; i < 4; ++i) bfv[i] = *(const v8s*)(&Bs[wn + i * 16 + r][q * 8]);
        #pragma unroll
        for (int i = 0; i < 4; ++i)
            #pragma unroll
            for (int jt = 0; jt < 4; ++jt)
                acc[i][jt] = __builtin_amdgcn_mfma_f32_16x16x32_bf16(af[i], bfv[jt], acc[i][jt], 0, 0, 0);
    }

    #pragma unroll
    for (int jt = 0; jt < 4; ++jt) {
        int j = tn * 128 + wn + jt * 16 + r;
        float bv = bias[j];
        #pragma unroll
        for (int i = 0; i < 4; ++i) {
            #pragma unroll
            for (int rr = 0; rr < 4; ++rr) {
                int m = tm * 128 + wm + i * 16 + q * 4 + rr;
                G[(size_t)m * 4096 + j] = acc[i][jt][rr] + bv;
            }
        }
    }
}

// ---------------------------------------------------------------------------
// One-shot Whh fp32 -> bf16 conversion (4096x1024 = 524288 groups of 8).
// ---------------------------------------------------------------------------
__global__ __launch_bounds__(256)
void conv_bf16(const float* __restrict__ src, ushort* __restrict__ dst)
{
    size_t i = (size_t)blockIdx.x * 256 + threadIdx.x;   // grid = 2048 blocks exact
    v8s v = load8_f32(src + i * 8);
    *(v8s*)(dst + i * 8) = v;
}

// ---------------------------------------------------------------------------
// Recurrence v2: NO cg::grid_sync (which wrote back + invalidated every XCD L2
// per step, forcing Whh/G refetch from LLC inside the MFMA dependent chain).
// Instead: hand-rolled grid barrier (relaxed device atomics + vmcnt discipline)
// and sc0/sc1 (LLC-coherent, L2-bypass) loads/stores for ONLY the h exchange.
// Whh (bf16, pre-converted if WB16) and G stay L2-resident across all steps.
// SRC16=1: stage h from bf16 circular buffer Hc[(t&15)][b][n].
// SRC16=0: stage h from fp32 Hf at (t&tmask)*stride_t + b*stride_b (fallback).
// Stores: bf16 -> Hc (if non-null), fp32 -> Hf (if non-null).
// ---------------------------------------------------------------------------
template<int SRC16, int WB16>
__global__ __launch_bounds__(256)
void lstm_recur2(const float* __restrict__ G, const void* __restrict__ Whv,
                 ushort* __restrict__ Hc, float* __restrict__ Hf,
                 float* __restrict__ Cst, float* __restrict__ oHT, float* __restrict__ oCT,
                 unsigned int* __restrict__ bar, unsigned int base,
                 int tstart, int nsteps, int tstep, int stride_t, int stride_b,
                 int tmask, int first, int tlast)
{
    __shared__ ushort hs[16][1032];       // +8 pad: spread LDS banks for b128 reads
    __shared__ float exch[3][16][17];     // f,g,o tiles -> wave 0

    const int blk = blockIdx.x;
    const int n0  = (blk & 63) << 4;
    const int b0  = (blk >> 6) << 4;
    const int tid = threadIdx.x;
    const int lane = tid & 63;
    const int w    = tid >> 6;
    const int r    = lane & 15;
    const int q    = lane >> 4;

    float creg[4] = {0.f, 0.f, 0.f, 0.f};
    if (w == 0 && !first) {
        #pragma unroll
        for (int rr = 0; rr < 4; ++rr)
            creg[rr] = Cst[(size_t)(b0 + q * 4 + rr) * NH + n0 + r];
    }
    const ushort* wrowh = (const ushort*)Whv + (size_t)(w * NH + n0 + r) * NH + q * 8;
    const float*  wrowf = (const float*) Whv + (size_t)(w * NH + n0 + r) * NH + q * 8;

    for (int s = 0; s < nsteps; ++s) {
        const int t = tstart + s * tstep;
        const bool have_h = !(first && s == 0);
        v4f acc = {0.f, 0.f, 0.f, 0.f};

        if (have_h) {
            const int tp = t - tstep;
            if (SRC16) {
                const size_t hbase = (size_t)(tp & (TC - 1)) * (BATCH * NH);
                v4i hr[8];
                #pragma unroll
                for (int j = 0; j < 8; ++j) {
                    int c = j * 256 + tid, row = c >> 7, k8 = (c & 127) << 3;
                    hr[j] = llc_load_i4(Hc + hbase + (size_t)(b0 + row) * NH + k8);
                }
                asm volatile("s_waitcnt vmcnt(0)" ::: "memory");
                __builtin_amdgcn_sched_barrier(0);
                #pragma unroll
                for (int j = 0; j < 8; ++j) {
                    int c = j * 256 + tid, row = c >> 7, k8 = (c & 127) << 3;
                    *(v4i*)(&hs[row][k8]) = hr[j];
                }
            } else {
                const size_t hbase = (size_t)(tp & tmask) * stride_t;
                #pragma unroll
                for (int half = 0; half < 2; ++half) {
                    v4f hr[8];
                    #pragma unroll
                    for (int j = 0; j < 4; ++j) {
                        int c = (half * 4 + j) * 256 + tid, row = c >> 7, k8 = (c & 127) << 3;
                        const float* src = Hf + hbase + (size_t)(b0 + row) * stride_b + k8;
                        hr[2 * j]     = llc_load_f4(src);
                        hr[2 * j + 1] = llc_load_f4(src + 4);
                    }
                    asm volatile("s_waitcnt vmcnt(0)" ::: "memory");
                    __builtin_amdgcn_sched_barrier(0);
                    #pragma unroll
                    for (int j = 0; j < 4; ++j) {
                        int c = (half * 4 + j) * 256 + tid, row = c >> 7, k8 = (c & 127) << 3;
                        ushort t8[8] = { f2bf(hr[2*j][0]),   f2bf(hr[2*j][1]),
                                         f2bf(hr[2*j][2]),   f2bf(hr[2*j][3]),
                                         f2bf(hr[2*j+1][0]), f2bf(hr[2*j+1][1]),
                                         f2bf(hr[2*j+1][2]), f2bf(hr[2*j+1][3]) };
                        *(v4i*)(&hs[row][k8]) = *(v4i*)t8;
                    }
                }
            }
        }
        __syncthreads();

        if (have_h) {
            #pragma unroll 8
            for (int kk = 0; kk < 32; ++kk) {
                v8s a = *(const v8s*)(&hs[r][kk * 32 + q * 8]);
                v8s b;
                if (WB16) b = *(const v8s*)(wrowh + kk * 32);   // plain load: L2-hit, stays warm
                else      b = load8_f32(wrowf + kk * 32);
                acc = __builtin_amdgcn_mfma_f32_16x16x32_bf16(a, b, acc, 0, 0, 0);
            }
        }
        const float* gt = G + ((size_t)s * BATCH + b0) * 4096 + w * NH + n0;
        #pragma unroll
        for (int rr = 0; rr < 4; ++rr)
            acc[rr] += __builtin_nontemporal_load(gt + (size_t)(q * 4 + rr) * 4096 + r);

        if (w > 0) {
            #pragma unroll
            for (int rr = 0; rr < 4; ++rr) exch[w - 1][q * 4 + rr][r] = acc[rr];
        }
        __syncthreads();

        if (w == 0) {
            #pragma unroll
            for (int rr = 0; rr < 4; ++rr) {
                int bl = q * 4 + rr;
                float iv = sigm(acc[rr]);
                float fv = sigm(exch[0][bl][r]);
                float gv = tanhx(exch[1][bl][r]);
                float ov = sigm(exch[2][bl][r]);
                float cc = fv * creg[rr] + iv * gv;
                creg[rr] = cc;
                float h  = ov * tanhx(cc);
                if (Hc) llc_store_u16(Hc + ((size_t)(t & (TC - 1)) * BATCH + (b0 + bl)) * NH + n0 + r,
                                      f2bf(h));
                if (Hf) llc_store_f32(Hf + (size_t)(t & tmask) * stride_t
                                         + (size_t)(b0 + bl) * stride_b + n0 + r, h);
                if (oHT != nullptr && t == tlast) {
                    oHT[(size_t)(b0 + bl) * NH + n0 + r] = h;
                    oCT[(size_t)(b0 + bl) * NH + n0 + r] = cc;
                }
            }
            // drain wave-0's sc stores to the coherence point before arriving
            asm volatile("s_waitcnt vmcnt(0)" ::: "memory");
        }
        // grid barrier: relaxed device-scope atomics, NO L2 writeback/invalidate
        if (tid == 0) {
            atomicAdd(bar, 1u);
            unsigned int tgt = base + (unsigned int)(s + 1) * 256u;
            while (llc_load_u32(bar) < tgt) __builtin_amdgcn_s_sleep(4);
        }
        __syncthreads();
    }
    if (w == 0) {
        #pragma unroll
        for (int rr = 0; rr < 4; ++rr)
            Cst[(size_t)(b0 + q * 4 + rr) * NH + n0 + r] = creg[rr];
    }
}

// ---------------------------------------------------------------------------
extern "C" void kernel_launch(void* const* d_in, const int* in_sizes, int n_in,
                              void* d_out, int out_size, void* d_ws, size_t ws_size,
                              hipStream_t stream)
{
    const float* X     = (const float*)d_in[0];
    const float* Wf_ih = (const float*)d_in[1];
    const float* Wf_hh = (const float*)d_in[2];
    const float* bf_b  = (const float*)d_in[3];
    const float* Wb_ih = (const float*)d_in[4];
    const float* Wb_hh = (const float*)d_in[5];
    const float* bb_b  = (const float*)d_in[6];
    const float* Wc_ih = (const float*)d_in[7];
    const float* Wc_hh = (const float*)d_in[8];
    const float* bc_b  = (const float*)d_in[9];

    float* enc = (float*)d_out;                        // [B][T][N] fp32; hosts hb then enc
    float* oHT = enc + (size_t)BATCH * T_SEQ * NH;     // [B][N]
    float* oCT = oHT + (size_t)BATCH * NH;             // [B][N]

    // ws: G | hfc | cstF | cstC | cstB | bar | [big: hbc | hcc | whF | whB | whC]
    char* ws = (char*)d_ws;
    const size_t G_BYTES  = (size_t)TC * BATCH * 4096 * 4;     // 16 MB
    const size_t HC_BYTES = (size_t)TC * BATCH * NH * 2;       // 2 MB
    const size_t C_BYTES  = (size_t)BATCH * NH * 4;            // 256 KB
    const size_t WH_BYTES = (size_t)4 * NH * NH * 2;           // 8 MB
    size_t off = 0;
    float*  G    = (float*)(ws + off);  off += G_BYTES;
    ushort* hfc  = (ushort*)(ws + off); off += HC_BYTES;
    float*  cstF = (float*)(ws + off);  off += C_BYTES;
    float*  cstC = (float*)(ws + off);  off += C_BYTES;
    float*  cstB = (float*)(ws + off);  off += C_BYTES;
    unsigned int* bar = (unsigned int*)(ws + off); off += 256;
    ushort* hbc  = (ushort*)(ws + off); off += HC_BYTES;
    ushort* hcc  = (ushort*)(ws + off); off += HC_BYTES;
    ushort* whF  = (ushort*)(ws + off); off += WH_BYTES;
    ushort* whB  = (ushort*)(ws + off); off += WH_BYTES;
    ushort* whC  = (ushort*)(ws + off); off += WH_BYTES;
    const bool big = (ws_size >= off);

    hipMemsetAsync(bar, 0, 4, stream);
    if (big) {
        conv_bf16<<<2048, 256, 0, stream>>>(Wf_hh, whF);
        conv_bf16<<<2048, 256, 0, stream>>>(Wb_hh, whB);
        conv_bf16<<<2048, 256, 0, stream>>>(Wc_hh, whC);
    }

    const int NCH = T_SEQ / TC;              // 32 chunks
    dim3 ggrid(TC * BATCH / 128, 32), gblk(256);
    const int FULLT = 0x7FFFFFFF;
    unsigned int base = 0;

    // 1) backward bilstm -> hb fp32 into enc region ([b][t][n]) + bf16 circular hbc
    for (int c = 0; c < NCH; ++c) {
        int ts = T_SEQ - 1 - c * TC;
        gates_gemm<<<ggrid, gblk, 0, stream>>>(X, (const ushort*)nullptr, (const float*)nullptr,
                                               Wb_ih, bb_b, G, ts, -1, 1024, 0);
        if (big)
            lstm_recur2<1, 1><<<256, 256, 0, stream>>>(G, whB, hbc, enc, cstB, nullptr, nullptr,
                bar, base, ts, TC, -1, NH, T_SEQ * NH, FULLT, c == 0 ? 1 : 0, -1);
        else
            lstm_recur2<0, 0><<<256, 256, 0, stream>>>(G, Wb_hh, nullptr, enc, cstB, nullptr, nullptr,
                bar, base, ts, TC, -1, NH, T_SEQ * NH, FULLT, c == 0 ? 1 : 0, -1);
        base += TC * 256;
    }
    // 2) forward bilstm + cell LSTM interleaved per chunk.
    for (int c = 0; c < NCH; ++c) {
        int ts = c * TC;
        gates_gemm<<<ggrid, gblk, 0, stream>>>(X, (const ushort*)nullptr, (const float*)nullptr,
                                               Wf_ih, bf_b, G, ts, 1, 1024, 0);
        if (big)
            lstm_recur2<1, 1><<<256, 256, 0, stream>>>(G, whF, hfc, nullptr, cstF, nullptr, nullptr,
                bar, base, ts, TC, 1, NH, NH, FULLT, c == 0 ? 1 : 0, -1);
        else
            lstm_recur2<1, 0><<<256, 256, 0, stream>>>(G, Wf_hh, hfc, nullptr, cstF, nullptr, nullptr,
                bar, base, ts, TC, 1, NH, NH, FULLT, c == 0 ? 1 : 0, -1);
        base += TC * 256;

        gates_gemm<<<ggrid, gblk, 0, stream>>>((const float*)nullptr, hfc, enc,
                                               Wc_ih, bc_b, G, ts, 1, 2048, 1);
        if (big)
            lstm_recur2<1, 1><<<256, 256, 0, stream>>>(G, whC, hcc, enc, cstC, oHT, oCT,
                bar, base, ts, TC, 1, NH, T_SEQ * NH, FULLT, c == 0 ? 1 : 0, T_SEQ - 1);
        else
            lstm_recur2<0, 0><<<256, 256, 0, stream>>>(G, Wc_hh, nullptr, enc, cstC, oHT, oCT,
                bar, base, ts, TC, 1, NH, T_SEQ * NH, FULLT, c == 0 ? 1 : 0, T_SEQ - 1);
        base += TC * 256;
    }
}

// Round 2
// 16396.217 us; speedup vs baseline: 5.6280x; 1.6036x over previous
//
#include <hip/hip_runtime.h>

typedef short v8s __attribute__((ext_vector_type(8)));
typedef float v4f __attribute__((ext_vector_type(4)));
typedef int   v4i __attribute__((ext_vector_type(4)));
typedef unsigned int u32;

#define T_SEQ 512
#define BATCH 64
#define NH    1024
#define TC    16   // time-chunk length (G buffer covers TC steps)

__device__ __forceinline__ ushort f2bf(float f) {
    union { float f; unsigned int i; } v; v.f = f;
    unsigned int x = v.i;
    return (ushort)((x + 0x7fffu + ((x >> 16) & 1u)) >> 16);
}
__device__ __forceinline__ float sigm(float x) { return 1.0f / (1.0f + __expf(-x)); }
__device__ __forceinline__ float tanhx(float x) {
    float e = __expf(2.0f * x);           // inf-safe: x>>0 -> 1, x<<0 -> -1
    return 1.0f - 2.0f / (e + 1.0f);
}
__device__ __forceinline__ void stage8_f32(ushort* dst, const float* src) {
    float4 a = *(const float4*)src;
    float4 b = *(const float4*)(src + 4);
    ushort t[8] = {f2bf(a.x), f2bf(a.y), f2bf(a.z), f2bf(a.w),
                   f2bf(b.x), f2bf(b.y), f2bf(b.z), f2bf(b.w)};
    *(int4*)dst = *(int4*)t;
}
__device__ __forceinline__ v8s load8_f32(const float* src) {
    float4 a = *(const float4*)src;
    float4 b = *(const float4*)(src + 4);
    ushort t[8] = {f2bf(a.x), f2bf(a.y), f2bf(a.z), f2bf(a.w),
                   f2bf(b.x), f2bf(b.y), f2bf(b.z), f2bf(b.w)};
    return *(v8s*)t;
}

// ---- device-coherent (LLC, L2-bypass) access helpers: sc0 sc1 -----------
__device__ __forceinline__ v4i llc_load_i4(const void* p) {
    v4i r;
    asm volatile("global_load_dwordx4 %0, %1, off sc0 sc1" : "=v"(r) : "v"(p));
    return r;
}
__device__ __forceinline__ v4f llc_load_f4(const float* p) {
    v4f r;
    asm volatile("global_load_dwordx4 %0, %1, off sc0 sc1" : "=v"(r) : "v"(p));
    return r;
}
__device__ __forceinline__ u32 llc_load_u32(const u32* p) {
    u32 r;
    asm volatile("global_load_dword %0, %1, off sc0 sc1\n\ts_waitcnt vmcnt(0)"
                 : "=v"(r) : "v"(p) : "memory");
    return r;
}
__device__ __forceinline__ void llc_store_f32(float* p, float v) {
    asm volatile("global_store_dword %0, %1, off sc0 sc1" :: "v"(p), "v"(v) : "memory");
}
__device__ __forceinline__ void llc_store_u16(ushort* p, ushort v) {
    unsigned int vv = v;
    asm volatile("global_store_short %0, %1, off sc0 sc1" :: "v"(p), "v"(vv) : "memory");
}
__device__ __forceinline__ void llc_store_b32(u32* p, u32 v) {
    asm volatile("global_store_dword %0, %1, off sc0 sc1" :: "v"(p), "v"(v) : "memory");
}

// ---------------------------------------------------------------------------
// Input-projection GEMM (unchanged).
// ---------------------------------------------------------------------------
__global__ __launch_bounds__(256)
void gates_gemm(const float* __restrict__ A0f, const ushort* __restrict__ A0h,
                const float* __restrict__ A1f,
                const float* __restrict__ W, const float* __restrict__ bias,
                float* __restrict__ G, int tstart, int tstep, int K, int mode)
{
    __shared__ ushort As[128][32];
    __shared__ ushort Bs[128][32];
    const int tid  = threadIdx.x;
    const int lane = tid & 63;
    const int wave = tid >> 6;
    const int wm   = (wave >> 1) * 64;
    const int wn   = (wave & 1) * 64;
    const int r    = lane & 15;
    const int q    = lane >> 4;
    const int tm   = blockIdx.x;
    const int tn   = blockIdx.y;

    v4f acc[4][4] = {};

    const int nkb = K >> 5;
    for (int kb = 0; kb < nkb; ++kb) {
        const int k0 = kb << 5;
        __syncthreads();
        #pragma unroll
        for (int j = 0; j < 2; ++j) {
            int c   = tid * 2 + j;
            int row = c >> 2;
            int k8  = (c & 3) << 3;
            int kg  = k0 + k8;
            int m = tm * 128 + row;
            int s = m >> 6, b = m & 63;
            if (mode == 0) {
                int t = tstart + s * tstep;
                stage8_f32(&As[row][k8], A0f + ((size_t)b * T_SEQ + t) * NH + kg);
            } else {
                int t = tstart + s;
                if (kg < NH) {
                    *(int4*)(&As[row][k8]) =
                        *(const int4*)(A0h + (((size_t)(t & (TC - 1)) * BATCH) + b) * NH + kg);
                } else {
                    stage8_f32(&As[row][k8], A1f + ((size_t)b * T_SEQ + t) * NH + (kg - NH));
                }
            }
            int jr = tn * 128 + row;
            stage8_f32(&Bs[row][k8], W + (size_t)jr * K + kg);
        }
        __syncthreads();
        v8s af[4], bfv[4];
        #pragma unroll
        for (int i = 0; i < 4; ++i) af[i]  = *(const v8s*)(&As[wm + i * 16 + r][q * 8]);
        #pragma unroll
        for (int i = 0; i < 4; ++i) bfv[i] = *(const v8s*)(&Bs[wn + i * 16 + r][q * 8]);
        #pragma unroll
        for (int i = 0; i < 4; ++i)
            #pragma unroll
            for (int jt = 0; jt < 4; ++jt)
                acc[i][jt] = __builtin_amdgcn_mfma_f32_16x16x32_bf16(af[i], bfv[jt], acc[i][jt], 0, 0, 0);
    }

    #pragma unroll
    for (int jt = 0; jt < 4; ++jt) {
        int j = tn * 128 + wn + jt * 16 + r;
        float bv = bias[j];
        #pragma unroll
        for (int i = 0; i < 4; ++i) {
            #pragma unroll
            for (int rr = 0; rr < 4; ++rr) {
                int m = tm * 128 + wm + i * 16 + q * 4 + rr;
                G[(size_t)m * 4096 + j] = acc[i][jt][rr] + bv;
            }
        }
    }
}

// ---------------------------------------------------------------------------
__global__ __launch_bounds__(256)
void conv_bf16(const float* __restrict__ src, ushort* __restrict__ dst)
{
    size_t i = (size_t)blockIdx.x * 256 + threadIdx.x;   // grid = 2048 exact
    v8s v = load8_f32(src + i * 8);
    *(v8s*)(dst + i * 8) = v;
}

// ---------------------------------------------------------------------------
// Recurrence core v3.
//  - Flag-array barrier per batch-group (64 producer blocks): block (nt,bt)
//    writes gflag[nt]=fbase+s+1 after its h stores are drained; consumers
//    poll all 64 flags with ONE coalesced sc load + __all().  No atomic RMW.
//  - Gate math + h stores distributed across all 4 waves (lane owns one
//    (row,col) of the 16x16 tile).
//  - G tile prefetched before the poll (independent of h).
// Max skew between blocks of a group is 1 step -> 16-slot circular h buffer
// is race-free.
// ---------------------------------------------------------------------------
template<int SRC16, int WB16>
__device__ __forceinline__ void recur_core(
    ushort (* __restrict__ hs)[1032], float (* __restrict__ exch)[16][17],
    int nt, int bt,
    const float* __restrict__ G, const void* __restrict__ Whv,
    ushort* __restrict__ Hc, float* __restrict__ Hf,
    float* __restrict__ Cst, float* __restrict__ oHT, float* __restrict__ oCT,
    u32* __restrict__ gflag, u32 fbase,
    int tstart, int nsteps, int tstep, int stride_t, int stride_b, int tmask,
    int first, int tlast)
{
    const int n0 = nt << 4, b0 = bt << 4;
    const int tid  = threadIdx.x;
    const int lane = tid & 63;
    const int w    = tid >> 6;
    const int r    = lane & 15;
    const int q    = lane >> 4;
    const int myrow = (w << 2) + q;     // this lane finalizes (myrow, mycol)
    const int mycol = r;

    float c_st = 0.f;
    if (!first) c_st = Cst[(size_t)(b0 + myrow) * NH + n0 + mycol];

    const ushort* wrowh = (const ushort*)Whv + (size_t)(w * NH + n0 + r) * NH + q * 8;
    const float*  wrowf = (const float*) Whv + (size_t)(w * NH + n0 + r) * NH + q * 8;

    for (int s = 0; s < nsteps; ++s) {
        const int t = tstart + s * tstep;
        const bool have_h = !(first && s == 0);
        v4f acc = {0.f, 0.f, 0.f, 0.f};

        // G prefetch: independent of h, issue before the barrier poll
        const float* gt = G + ((size_t)s * BATCH + b0) * 4096 + w * NH + n0;
        float gvv[4];
        #pragma unroll
        for (int rr = 0; rr < 4; ++rr)
            gvv[rr] = __builtin_nontemporal_load(gt + (size_t)(q * 4 + rr) * 4096 + r);

        if (have_h) {
            // wait until every producer of h(t - tstep) has published
            const u32 tgt = fbase + (u32)s;
            u32 fv = llc_load_u32(gflag + lane);
            while (!__all((int)(fv >= tgt))) {
                __builtin_amdgcn_s_sleep(1);
                fv = llc_load_u32(gflag + lane);
            }
            const int tp = t - tstep;
            if (SRC16) {
                const size_t hbase = (size_t)(tp & (TC - 1)) * (BATCH * NH);
                v4i hr[8];
                #pragma unroll
                for (int j = 0; j < 8; ++j) {
                    int c = j * 256 + tid, row = c >> 7, k8 = (c & 127) << 3;
                    hr[j] = llc_load_i4(Hc + hbase + (size_t)(b0 + row) * NH + k8);
                }
                asm volatile("s_waitcnt vmcnt(0)" ::: "memory");
                __builtin_amdgcn_sched_barrier(0);
                #pragma unroll
                for (int j = 0; j < 8; ++j) {
                    int c = j * 256 + tid, row = c >> 7, k8 = (c & 127) << 3;
                    *(v4i*)(&hs[row][k8]) = hr[j];
                }
            } else {
                const size_t hbase = (size_t)(tp & tmask) * stride_t;
                #pragma unroll
                for (int half = 0; half < 2; ++half) {
                    v4f hr[8];
                    #pragma unroll
                    for (int j = 0; j < 4; ++j) {
                        int c = (half * 4 + j) * 256 + tid, row = c >> 7, k8 = (c & 127) << 3;
                        const float* src = Hf + hbase + (size_t)(b0 + row) * stride_b + k8;
                        hr[2 * j]     = llc_load_f4(src);
                        hr[2 * j + 1] = llc_load_f4(src + 4);
                    }
                    asm volatile("s_waitcnt vmcnt(0)" ::: "memory");
                    __builtin_amdgcn_sched_barrier(0);
                    #pragma unroll
                    for (int j = 0; j < 4; ++j) {
                        int c = (half * 4 + j) * 256 + tid, row = c >> 7, k8 = (c & 127) << 3;
                        ushort t8[8] = { f2bf(hr[2*j][0]),   f2bf(hr[2*j][1]),
                                         f2bf(hr[2*j][2]),   f2bf(hr[2*j][3]),
                                         f2bf(hr[2*j+1][0]), f2bf(hr[2*j+1][1]),
                                         f2bf(hr[2*j+1][2]), f2bf(hr[2*j+1][3]) };
                        *(v4i*)(&hs[row][k8]) = *(v4i*)t8;
                    }
                }
            }
        }
        __syncthreads();

        if (have_h) {
            #pragma unroll 8
            for (int kk = 0; kk < 32; ++kk) {
                v8s a = *(const v8s*)(&hs[r][kk * 32 + q * 8]);
                v8s b;
                if (WB16) b = *(const v8s*)(wrowh + kk * 32);   // L2-warm
                else      b = load8_f32(wrowf + kk * 32);
                acc = __builtin_amdgcn_mfma_f32_16x16x32_bf16(a, b, acc, 0, 0, 0);
            }
        }
        #pragma unroll
        for (int rr = 0; rr < 4; ++rr) acc[rr] += gvv[rr];

        // all-gate exchange (wave w holds gate w's [16x16] tile)
        #pragma unroll
        for (int rr = 0; rr < 4; ++rr) exch[w][q * 4 + rr][r] = acc[rr];
        __syncthreads();

        {
            float iv = sigm(exch[0][myrow][mycol]);
            float fg = sigm(exch[1][myrow][mycol]);
            float gv = tanhx(exch[2][myrow][mycol]);
            float ov = sigm(exch[3][myrow][mycol]);
            float cc = fg * c_st + iv * gv;
            c_st = cc;
            float h  = ov * tanhx(cc);
            if (Hc) llc_store_u16(Hc + ((size_t)(t & (TC - 1)) * BATCH + (b0 + myrow)) * NH + n0 + mycol,
                                  f2bf(h));
            if (Hf) llc_store_f32(Hf + (size_t)(t & tmask) * stride_t
                                     + (size_t)(b0 + myrow) * stride_b + n0 + mycol, h);
            if (oHT != nullptr && t == tlast) {
                oHT[(size_t)(b0 + myrow) * NH + n0 + mycol] = h;
                oCT[(size_t)(b0 + myrow) * NH + n0 + mycol] = cc;
            }
        }
        asm volatile("s_waitcnt vmcnt(0)" ::: "memory");   // drain this wave's h stores
        __syncthreads();                                   // all waves drained
        if (tid == 0) llc_store_b32(gflag + nt, fbase + (u32)(s + 1));
    }
    Cst[(size_t)(b0 + myrow) * NH + n0 + mycol] = c_st;
}

// 256-block single recurrence. XCD swizzle: blocks sharing Whh rows (same nt
// range) land on the same XCD's L2.
template<int SRC16, int WB16>
__global__ __launch_bounds__(256)
void recur1(const float* __restrict__ G, const void* __restrict__ Wh,
            ushort* __restrict__ Hc, float* __restrict__ Hf,
            float* __restrict__ Cst, float* __restrict__ oHT, float* __restrict__ oCT,
            u32* __restrict__ flags, u32 fbase,
            int tstart, int nsteps, int tstep, int stride_t, int stride_b, int tmask,
            int first, int tlast)
{
    __shared__ ushort hs[16][1032];
    __shared__ float exch[4][16][17];
    const int i = blockIdx.x, xcd = i & 7, j = i >> 3;   // j in 0..31
    const int bt = j & 3, nt = xcd * 8 + (j >> 2);
    recur_core<SRC16, WB16>(hs, exch, nt, bt, G, Wh, Hc, Hf, Cst, oHT, oCT,
                            flags + bt * 64, fbase, tstart, nsteps, tstep,
                            stride_t, stride_b, tmask, first, tlast);
}

// 512-block fused fwd (dir 0, groups 0-3) + cell (dir 1, groups 4-7).
template<int WB16>
__global__ __launch_bounds__(256)
void fused_fc(const float* __restrict__ Gf, const float* __restrict__ Gc,
              const void* __restrict__ whF, const void* __restrict__ whC,
              ushort* __restrict__ hfc, ushort* __restrict__ hcc,
              float* __restrict__ enc, float* __restrict__ cstF, float* __restrict__ cstC,
              float* __restrict__ oHT, float* __restrict__ oCT,
              u32* __restrict__ flags, u32 fb03, u32 fb47,
              int tsF, int tsC, int firstC)
{
    __shared__ ushort hs[16][1032];
    __shared__ float exch[4][16][17];
    const int i = blockIdx.x, xcd = i & 7, j = i >> 3;   // j in 0..63
    const int dir = j & 1, bt = (j >> 1) & 3, nt = xcd * 8 + (j >> 3);
    if (dir == 0)
        recur_core<1, WB16>(hs, exch, nt, bt, Gf, whF, hfc, nullptr, cstF, nullptr, nullptr,
                            flags + bt * 64, fb03, tsF, TC, 1, NH, NH, 0x7FFFFFFF, 0, -1);
    else
        recur_core<1, WB16>(hs, exch, nt, bt, Gc, whC, hcc, enc, cstC, oHT, oCT,
                            flags + (4 + bt) * 64, fb47, tsC, TC, 1, NH, T_SEQ * NH, 0x7FFFFFFF,
                            firstC, T_SEQ - 1);
}

// ---------------------------------------------------------------------------
extern "C" void kernel_launch(void* const* d_in, const int* in_sizes, int n_in,
                              void* d_out, int out_size, void* d_ws, size_t ws_size,
                              hipStream_t stream)
{
    const float* X     = (const float*)d_in[0];
    const float* Wf_ih = (const float*)d_in[1];
    const float* Wf_hh = (const float*)d_in[2];
    const float* bf_b  = (const float*)d_in[3];
    const float* Wb_ih = (const float*)d_in[4];
    const float* Wb_hh = (const float*)d_in[5];
    const float* bb_b  = (const float*)d_in[6];
    const float* Wc_ih = (const float*)d_in[7];
    const float* Wc_hh = (const float*)d_in[8];
    const float* bc_b  = (const float*)d_in[9];

    float* enc = (float*)d_out;                        // [B][T][N] fp32; hosts hb then enc
    float* oHT = enc + (size_t)BATCH * T_SEQ * NH;
    float* oCT = oHT + (size_t)BATCH * NH;

    // ws layout (tiered): Gf | hfc | cstF|cstC|cstB | flags || hbc | hcc | whF|whB|whC || Gc
    char* ws = (char*)d_ws;
    const size_t G_BYTES    = (size_t)TC * BATCH * 4096 * 4;   // 16 MB
    const size_t HC_BYTES   = (size_t)TC * BATCH * NH * 2;     // 2 MB
    const size_t C_BYTES    = (size_t)BATCH * NH * 4;          // 256 KB
    const size_t WH_BYTES   = (size_t)4 * NH * NH * 2;         // 8 MB
    const size_t FLAG_BYTES = 4096;
    size_t off = 0;
    float*  Gf   = (float*)(ws + off);  off += G_BYTES;
    ushort* hfc  = (ushort*)(ws + off); off += HC_BYTES;
    float*  cstF = (float*)(ws + off);  off += C_BYTES;
    float*  cstC = (float*)(ws + off);  off += C_BYTES;
    float*  cstB = (float*)(ws + off);  off += C_BYTES;
    u32*    flags= (u32*)(ws + off);    off += FLAG_BYTES;
    ushort* hbc  = (ushort*)(ws + off); off += HC_BYTES;
    ushort* hcc  = (ushort*)(ws + off); off += HC_BYTES;
    ushort* whF  = (ushort*)(ws + off); off += WH_BYTES;
    ushort* whB  = (ushort*)(ws + off); off += WH_BYTES;
    ushort* whC  = (ushort*)(ws + off); off += WH_BYTES;
    const size_t off_t1 = off;
    float*  Gc   = (float*)(ws + off);  off += G_BYTES;
    const size_t off_t2 = off;
    const int tier = (ws_size >= off_t2) ? 2 : (ws_size >= off_t1 ? 1 : 0);

    hipMemsetAsync(flags, 0, FLAG_BYTES, stream);
    if (tier >= 1) {
        conv_bf16<<<2048, 256, 0, stream>>>(Wf_hh, whF);
        conv_bf16<<<2048, 256, 0, stream>>>(Wb_hh, whB);
        conv_bf16<<<2048, 256, 0, stream>>>(Wc_hh, whC);
    }

    const int NCH = T_SEQ / TC;              // 32
    dim3 ggrid(TC * BATCH / 128, 32), gblk(256);
    const int FULLT = 0x7FFFFFFF;
    u32 fb = 0;                              // flag groups 0-3 (bwd, then fwd)

    // Phase 1: backward bilstm -> hb fp32 into enc ([b][t][n]) + bf16 circular hbc
    for (int c = 0; c < NCH; ++c) {
        int ts = T_SEQ - 1 - c * TC;
        gates_gemm<<<ggrid, gblk, 0, stream>>>(X, (const ushort*)nullptr, (const float*)nullptr,
                                               Wb_ih, bb_b, Gf, ts, -1, 1024, 0);
        if (tier >= 1)
            recur1<1, 1><<<256, 256, 0, stream>>>(Gf, whB, hbc, enc, cstB, nullptr, nullptr,
                flags, fb, ts, TC, -1, NH, T_SEQ * NH, FULLT, c == 0 ? 1 : 0, -1);
        else
            recur1<0, 0><<<256, 256, 0, stream>>>(Gf, Wb_hh, nullptr, enc, cstB, nullptr, nullptr,
                flags, fb, ts, TC, -1, NH, T_SEQ * NH, FULLT, c == 0 ? 1 : 0, -1);
        fb += TC;
    }

    if (tier == 2) {
        // Phase 2: fwd chunk d fused with cell chunk d-1 (one-chunk lag).
        u32 fb47 = 0;
        for (int d = 0; d <= NCH; ++d) {
            if (d < NCH)
                gates_gemm<<<ggrid, gblk, 0, stream>>>(X, (const ushort*)nullptr, (const float*)nullptr,
                                                       Wf_ih, bf_b, Gf, d * TC, 1, 1024, 0);
            if (d >= 1)
                gates_gemm<<<ggrid, gblk, 0, stream>>>((const float*)nullptr, hfc, enc,
                                                       Wc_ih, bc_b, Gc, (d - 1) * TC, 1, 2048, 1);
            if (d == 0) {
                recur1<1, 1><<<256, 256, 0, stream>>>(Gf, whF, hfc, nullptr, cstF, nullptr, nullptr,
                    flags, fb, 0, TC, 1, NH, NH, FULLT, 1, -1);
                fb += TC;
            } else if (d < NCH) {
                fused_fc<1><<<512, 256, 0, stream>>>(Gf, Gc, whF, whC, hfc, hcc, enc, cstF, cstC,
                    oHT, oCT, flags, fb, fb47, d * TC, (d - 1) * TC, d == 1 ? 1 : 0);
                fb += TC; fb47 += TC;
            } else {
                recur1<1, 1><<<256, 256, 0, stream>>>(Gc, whC, hcc, enc, cstC, oHT, oCT,
                    flags + 256, fb47, (d - 1) * TC, TC, 1, NH, T_SEQ * NH, FULLT, 0, T_SEQ - 1);
                fb47 += TC;
            }
        }
    } else {
        // Fallback: sequential fwd+cell interleave (round-1 structure, flag barrier)
        for (int c = 0; c < NCH; ++c) {
            int ts = c * TC;
            gates_gemm<<<ggrid, gblk, 0, stream>>>(X, (const ushort*)nullptr, (const float*)nullptr,
                                                   Wf_ih, bf_b, Gf, ts, 1, 1024, 0);
            if (tier >= 1)
                recur1<1, 1><<<256, 256, 0, stream>>>(Gf, whF, hfc, nullptr, cstF, nullptr, nullptr,
                    flags, fb, ts, TC, 1, NH, NH, FULLT, c == 0 ? 1 : 0, -1);
            else
                recur1<1, 0><<<256, 256, 0, stream>>>(Gf, Wf_hh, hfc, nullptr, cstF, nullptr, nullptr,
                    flags, fb, ts, TC, 1, NH, NH, FULLT, c == 0 ? 1 : 0, -1);
            fb += TC;

            gates_gemm<<<ggrid, gblk, 0, stream>>>((const float*)nullptr, hfc, enc,
                                                   Wc_ih, bc_b, Gf, ts, 1, 2048, 1);
            if (tier >= 1)
                recur1<1, 1><<<256, 256, 0, stream>>>(Gf, whC, hcc, enc, cstC, oHT, oCT,
                    flags, fb, ts, TC, 1, NH, T_SEQ * NH, FULLT, c == 0 ? 1 : 0, T_SEQ - 1);
            else
                recur1<0, 0><<<256, 256, 0, stream>>>(Gf, Wc_hh, nullptr, enc, cstC, oHT, oCT,
                    flags, fb, ts, TC, 1, NH, T_SEQ * NH, FULLT, c == 0 ? 1 : 0, T_SEQ - 1);
            fb += TC;
        }
    }
}